// Round 1
// baseline (184.782 us; speedup 1.0000x reference)
//
#include <hip/hip_runtime.h>
#include <hip/hip_bf16.h>
#include <stdint.h>
#include <math.h>

// Problem dims
#define B_    1024
#define LAT   64
#define FCON  256
#define IN_SZ 320          // LAT + FCON
#define HID   512
#define E_    8
#define GH    64
#define INTER 576          // LAT + HID
#define OUT_SZ 512
#define NTOT  4096         // E_ * 512

typedef __attribute__((ext_vector_type(8))) __bf16 bf16x8;
typedef __attribute__((ext_vector_type(4))) float  f32x4;

__device__ __forceinline__ float elu_f(float x) { return x > 0.f ? x : expf(x) - 1.f; }

// ---------------------------------------------------------------------------
// Convert z,c -> bf16 x0=[z|c] (K=320); also seed z into x1[:, :64], x2[:, :64]
// ---------------------------------------------------------------------------
__global__ __launch_bounds__(256) void xconv_kernel(
    const float* __restrict__ z, const float* __restrict__ c,
    __hip_bfloat16* __restrict__ x0, __hip_bfloat16* __restrict__ x1,
    __hip_bfloat16* __restrict__ x2)
{
    int idx = blockIdx.x * 256 + threadIdx.x;      // B_*IN_SZ threads exactly
    int row = idx / IN_SZ, col = idx % IN_SZ;
    float v = (col < LAT) ? z[row * LAT + col] : c[row * FCON + (col - LAT)];
    __hip_bfloat16 bv = __float2bfloat16(v);
    x0[row * IN_SZ + col] = bv;
    if (col < LAT) {
        x1[row * INTER + col] = bv;
        x2[row * INTER + col] = bv;
    }
}

// ---------------------------------------------------------------------------
// Weight convert+transpose: w [E,K,512] f32  ->  wT [4096, K] bf16
//   wT[e*512+o][k] = w[e][k][o]
// grid (512/32, K/32, 8), block (32,8)
// ---------------------------------------------------------------------------
__global__ __launch_bounds__(256) void wconv_kernel(
    const float* __restrict__ w, __hip_bfloat16* __restrict__ wT, int K)
{
    __shared__ float tile[32][33];
    const int e  = blockIdx.z;
    const int o0 = blockIdx.x * 32;
    const int k0 = blockIdx.y * 32;
    const int tx = threadIdx.x, ty = threadIdx.y;
    const float* we = w + (size_t)e * K * 512;
#pragma unroll
    for (int i = 0; i < 4; i++)
        tile[ty + i * 8][tx] = we[(size_t)(k0 + ty + i * 8) * 512 + o0 + tx];
    __syncthreads();
#pragma unroll
    for (int i = 0; i < 4; i++)
        wT[(size_t)(e * 512 + o0 + ty + i * 8) * K + k0 + tx] =
            __float2bfloat16(tile[tx][ty + i * 8]);
}

// ---------------------------------------------------------------------------
// Gating network: coeff[b,e] = softmax(elu(elu(x@gw1+gb1)@gw2+gb2)@gw3+gb3)
// One wave per row; block = 4 waves; grid = 256.
// ---------------------------------------------------------------------------
__global__ __launch_bounds__(256) void gate_kernel(
    const float* __restrict__ z, const float* __restrict__ c,
    const float* __restrict__ gw1, const float* __restrict__ gb1,
    const float* __restrict__ gw2, const float* __restrict__ gb2,
    const float* __restrict__ gw3, const float* __restrict__ gb3,
    float* __restrict__ coeff)
{
    __shared__ float h[4][GH];
    __shared__ float lg[4][E_];
    const int lane = threadIdx.x & 63, wave = threadIdx.x >> 6;
    const int row = blockIdx.x * 4 + wave;
    const float* zr = z + (size_t)row * LAT;
    const float* cr = c + (size_t)row * FCON;

    float a1 = gb1[lane];
    for (int i = 0; i < LAT; i++)  a1 = fmaf(zr[i], gw1[i * GH + lane], a1);
    for (int i = 0; i < FCON; i++) a1 = fmaf(cr[i], gw1[(LAT + i) * GH + lane], a1);
    h[wave][lane] = elu_f(a1);
    __syncthreads();

    float a2 = gb2[lane];
    for (int i = 0; i < GH; i++) a2 = fmaf(h[wave][i], gw2[i * GH + lane], a2);
    a2 = elu_f(a2);
    __syncthreads();
    h[wave][lane] = a2;
    __syncthreads();

    if (lane < E_) {
        float a3 = gb3[lane];
        for (int i = 0; i < GH; i++) a3 = fmaf(h[wave][i], gw3[i * E_ + lane], a3);
        lg[wave][lane] = a3;
    }
    __syncthreads();
    if (lane < E_) {
        float mx = lg[wave][0];
        for (int i = 1; i < E_; i++) mx = fmaxf(mx, lg[wave][i]);
        float s = 0.f;
        for (int i = 0; i < E_; i++) s += expf(lg[wave][i] - mx);
        coeff[(size_t)row * E_ + lane] = expf(lg[wave][lane] - mx) / s;
    }
}

// ---------------------------------------------------------------------------
// bf16 GEMM (m97 structure): Y[M, 4096] f32 = A[M,K] * Bt[4096,K]^T
// 128x128 block tile, BK=32, 4 waves x (64x64), mfma_f32_16x16x32_bf16.
// grid (4096/128=32, M/128), block 256.
// ---------------------------------------------------------------------------
__global__ __launch_bounds__(256) void gemm_bt(
    const __hip_bfloat16* __restrict__ A,
    const __hip_bfloat16* __restrict__ Bt,
    float* __restrict__ Y,
    int K)
{
    __shared__ __hip_bfloat16 As[128 * 32];
    __shared__ __hip_bfloat16 Bs[128 * 32];
    const int t = threadIdx.x;
    const int lane = t & 63, wave = t >> 6;
    const int n0 = blockIdx.x * 128;
    const int m0 = blockIdx.y * 128;
    const int mw = (wave >> 1) * 64, nw = (wave & 1) * 64;
    const int q = lane >> 4, r = lane & 15;
    const int rowc = lane >> 2, c16 = lane & 3;

    f32x4 acc[4][4];
#pragma unroll
    for (int i = 0; i < 4; i++)
#pragma unroll
        for (int j = 0; j < 4; j++) acc[i][j] = (f32x4){0.f, 0.f, 0.f, 0.f};

    for (int k0 = 0; k0 < K; k0 += 32) {
        __syncthreads();
#pragma unroll
        for (int i = 0; i < 2; i++) {
            const int ch = wave * 2 + i;     // 16-row chunk, 1 KiB per wave-instr
            const __hip_bfloat16* ga = A + (size_t)(m0 + ch * 16 + rowc) * K + (k0 + c16 * 8);
            __builtin_amdgcn_global_load_lds(
                (const __attribute__((address_space(1))) void*)ga,
                (__attribute__((address_space(3))) void*)(As + ch * 512), 16, 0, 0);
            const __hip_bfloat16* gb = Bt + (size_t)(n0 + ch * 16 + rowc) * K + (k0 + c16 * 8);
            __builtin_amdgcn_global_load_lds(
                (const __attribute__((address_space(1))) void*)gb,
                (__attribute__((address_space(3))) void*)(Bs + ch * 512), 16, 0, 0);
        }
        __syncthreads();   // drains vmcnt(0): staged data visible to all waves

        bf16x8 af[4], bf[4];
#pragma unroll
        for (int im = 0; im < 4; im++)
            af[im] = *(const bf16x8*)(As + (mw + im * 16 + r) * 32 + q * 8);
#pragma unroll
        for (int in = 0; in < 4; in++)
            bf[in] = *(const bf16x8*)(Bs + (nw + in * 16 + r) * 32 + q * 8);
#pragma unroll
        for (int im = 0; im < 4; im++)
#pragma unroll
            for (int in = 0; in < 4; in++)
                acc[im][in] = __builtin_amdgcn_mfma_f32_16x16x32_bf16(
                    af[im], bf[in], acc[im][in], 0, 0, 0);
    }

    // Epilogue: D layout col=lane&15, row=(lane>>4)*4+reg  [m89-verified]
#pragma unroll
    for (int im = 0; im < 4; im++)
#pragma unroll
        for (int in = 0; in < 4; in++) {
            const int n = n0 + nw + in * 16 + r;
#pragma unroll
            for (int v = 0; v < 4; v++) {
                const int m = m0 + mw + im * 16 + q * 4 + v;
                Y[(size_t)m * NTOT + n] = acc[im][in][v];
            }
        }
}

// ---------------------------------------------------------------------------
// Expert reduce: out[b,o] = act( sum_e coeff[b,e] * (Y[b,e*512+o] + bias[e,o]) )
// Writes bf16 into xnext[:, 64:576] (layers 0,1) or f32 into fout (layer 2).
// grid 512, block 256; each thread does 4 columns (float4).
// ---------------------------------------------------------------------------
__global__ __launch_bounds__(256) void reduce_kernel(
    const float* __restrict__ Y, const float* __restrict__ coeff,
    const float* __restrict__ bias,
    __hip_bfloat16* __restrict__ xnext, float* __restrict__ fout,
    int applyElu)
{
    const int idx = blockIdx.x * 256 + threadIdx.x;   // B_*128 exactly
    const int b = idx >> 7;
    const int o = (idx & 127) * 4;
    const float* cb = coeff + (size_t)b * E_;
    f32x4 s = (f32x4){0.f, 0.f, 0.f, 0.f};
#pragma unroll
    for (int e = 0; e < E_; e++) {
        const float ce = cb[e];
        const f32x4 y  = *(const f32x4*)(Y + (size_t)b * NTOT + e * 512 + o);
        const f32x4 bs = *(const f32x4*)(bias + (size_t)e * 512 + o);
#pragma unroll
        for (int v = 0; v < 4; v++) s[v] += ce * (y[v] + bs[v]);
    }
    if (applyElu) {
#pragma unroll
        for (int v = 0; v < 4; v++) s[v] = elu_f(s[v]);
    }
    if (xnext) {
#pragma unroll
        for (int v = 0; v < 4; v++)
            xnext[(size_t)b * INTER + LAT + o + v] = __float2bfloat16(s[v]);
    } else {
#pragma unroll
        for (int v = 0; v < 4; v++) fout[(size_t)b * OUT_SZ + o + v] = s[v];
    }
}

// ---------------------------------------------------------------------------
static inline size_t align256(size_t x) { return (x + 255) & ~(size_t)255; }

extern "C" void kernel_launch(void* const* d_in, const int* in_sizes, int n_in,
                              void* d_out, int out_size, void* d_ws, size_t ws_size,
                              hipStream_t stream)
{
    const float* z   = (const float*)d_in[0];
    const float* c   = (const float*)d_in[1];
    const float* w0  = (const float*)d_in[2];
    const float* b0  = (const float*)d_in[3];
    const float* w1  = (const float*)d_in[4];
    const float* b1  = (const float*)d_in[5];
    const float* w2  = (const float*)d_in[6];
    const float* b2  = (const float*)d_in[7];
    const float* gw1 = (const float*)d_in[8];
    const float* gb1 = (const float*)d_in[9];
    const float* gw2 = (const float*)d_in[10];
    const float* gb2 = (const float*)d_in[11];
    const float* gw3 = (const float*)d_in[12];
    const float* gb3 = (const float*)d_in[13];
    float* out = (float*)d_out;

    uint8_t* p = (uint8_t*)d_ws;
    __hip_bfloat16* wT0 = (__hip_bfloat16*)p; p += align256((size_t)NTOT * IN_SZ * 2);
    __hip_bfloat16* wT1 = (__hip_bfloat16*)p; p += align256((size_t)NTOT * INTER * 2);
    __hip_bfloat16* wT2 = (__hip_bfloat16*)p; p += align256((size_t)NTOT * INTER * 2);
    __hip_bfloat16* x0  = (__hip_bfloat16*)p; p += align256((size_t)B_ * IN_SZ * 2);
    __hip_bfloat16* x1  = (__hip_bfloat16*)p; p += align256((size_t)B_ * INTER * 2);
    __hip_bfloat16* x2  = (__hip_bfloat16*)p; p += align256((size_t)B_ * INTER * 2);
    float* coeff        = (float*)p;          p += align256((size_t)B_ * E_ * 4);
    float* Y            = (float*)p;          p += align256((size_t)B_ * NTOT * 4);

    // 1) activations -> bf16
    xconv_kernel<<<(B_ * IN_SZ) / 256, 256, 0, stream>>>(z, c, x0, x1, x2);
    // 2) weights -> bf16 transposed [4096, K]
    wconv_kernel<<<dim3(16, IN_SZ / 32, E_), dim3(32, 8), 0, stream>>>(w0, wT0, IN_SZ);
    wconv_kernel<<<dim3(16, INTER / 32, E_), dim3(32, 8), 0, stream>>>(w1, wT1, INTER);
    wconv_kernel<<<dim3(16, INTER / 32, E_), dim3(32, 8), 0, stream>>>(w2, wT2, INTER);
    // 3) gating coefficients (f32 exact)
    gate_kernel<<<B_ / 4, 256, 0, stream>>>(z, c, gw1, gb1, gw2, gb2, gw3, gb3, coeff);

    // 4) layer 0: Y = x0 @ W0cat ; out0 = elu(reduce) -> x1[:,64:]
    gemm_bt<<<dim3(NTOT / 128, B_ / 128), 256, 0, stream>>>(x0, wT0, Y, IN_SZ);
    reduce_kernel<<<(B_ * 128) / 256, 256, 0, stream>>>(Y, coeff, b0, x1, nullptr, 1);
    // 5) layer 1
    gemm_bt<<<dim3(NTOT / 128, B_ / 128), 256, 0, stream>>>(x1, wT1, Y, INTER);
    reduce_kernel<<<(B_ * 128) / 256, 256, 0, stream>>>(Y, coeff, b1, x2, nullptr, 1);
    // 6) layer 2 -> d_out (f32, no act)
    gemm_bt<<<dim3(NTOT / 128, B_ / 128), 256, 0, stream>>>(x2, wT2, Y, INTER);
    reduce_kernel<<<(B_ * 128) / 256, 256, 0, stream>>>(Y, coeff, b2, nullptr, out, 0);
}

// Round 2
// 171.814 us; speedup vs baseline: 1.0755x; 1.0755x over previous
//
#include <hip/hip_runtime.h>
#include <hip/hip_bf16.h>
#include <stdint.h>
#include <math.h>

// Problem dims
#define B_    1024
#define LAT   64
#define FCON  256
#define IN_SZ 320          // LAT + FCON
#define HID   512
#define E_    8
#define GH    64
#define INTER 576          // LAT + HID
#define OUT_SZ 512
#define NTOT  4096         // E_ * 512

typedef __attribute__((ext_vector_type(8))) __bf16 bf16x8;
typedef __attribute__((ext_vector_type(4))) float  f32x4;

__device__ __forceinline__ float elu_f(float x) { return x > 0.f ? x : expf(x) - 1.f; }

// ---------------------------------------------------------------------------
// Convert z,c -> bf16 x0=[z|c] (K=320); also seed z into x1[:, :64], x2[:, :64]
// ---------------------------------------------------------------------------
__global__ __launch_bounds__(256) void xconv_kernel(
    const float* __restrict__ z, const float* __restrict__ c,
    __hip_bfloat16* __restrict__ x0, __hip_bfloat16* __restrict__ x1,
    __hip_bfloat16* __restrict__ x2)
{
    int idx = blockIdx.x * 256 + threadIdx.x;      // B_*IN_SZ threads exactly
    int row = idx / IN_SZ, col = idx % IN_SZ;
    float v = (col < LAT) ? z[row * LAT + col] : c[row * FCON + (col - LAT)];
    __hip_bfloat16 bv = __float2bfloat16(v);
    x0[row * IN_SZ + col] = bv;
    if (col < LAT) {
        x1[row * INTER + col] = bv;
        x2[row * INTER + col] = bv;
    }
}

// ---------------------------------------------------------------------------
// Weight convert+transpose: w [E,K,512] f32  ->  wT [4096, K] bf16
//   wT[e*512+o][k] = w[e][k][o]
// grid (512/32, K/32, 8), block (32,8)
// ---------------------------------------------------------------------------
__global__ __launch_bounds__(256) void wconv_kernel(
    const float* __restrict__ w, __hip_bfloat16* __restrict__ wT, int K)
{
    __shared__ float tile[32][33];
    const int e  = blockIdx.z;
    const int o0 = blockIdx.x * 32;
    const int k0 = blockIdx.y * 32;
    const int tx = threadIdx.x, ty = threadIdx.y;
    const float* we = w + (size_t)e * K * 512;
#pragma unroll
    for (int i = 0; i < 4; i++)
        tile[ty + i * 8][tx] = we[(size_t)(k0 + ty + i * 8) * 512 + o0 + tx];
    __syncthreads();
#pragma unroll
    for (int i = 0; i < 4; i++)
        wT[(size_t)(e * 512 + o0 + ty + i * 8) * K + k0 + tx] =
            __float2bfloat16(tile[tx][ty + i * 8]);
}

// ---------------------------------------------------------------------------
// Gating network: coeff[b,e] = softmax(elu(elu(x@gw1+gb1)@gw2+gb2)@gw3+gb3)
// One wave per row; block = 4 waves; grid = 256.
// ---------------------------------------------------------------------------
__global__ __launch_bounds__(256) void gate_kernel(
    const float* __restrict__ z, const float* __restrict__ c,
    const float* __restrict__ gw1, const float* __restrict__ gb1,
    const float* __restrict__ gw2, const float* __restrict__ gb2,
    const float* __restrict__ gw3, const float* __restrict__ gb3,
    float* __restrict__ coeff)
{
    __shared__ float h[4][GH];
    __shared__ float lg[4][E_];
    const int lane = threadIdx.x & 63, wave = threadIdx.x >> 6;
    const int row = blockIdx.x * 4 + wave;
    const float* zr = z + (size_t)row * LAT;
    const float* cr = c + (size_t)row * FCON;

    float a1 = gb1[lane];
    for (int i = 0; i < LAT; i++)  a1 = fmaf(zr[i], gw1[i * GH + lane], a1);
    for (int i = 0; i < FCON; i++) a1 = fmaf(cr[i], gw1[(LAT + i) * GH + lane], a1);
    h[wave][lane] = elu_f(a1);
    __syncthreads();

    float a2 = gb2[lane];
    for (int i = 0; i < GH; i++) a2 = fmaf(h[wave][i], gw2[i * GH + lane], a2);
    a2 = elu_f(a2);
    __syncthreads();
    h[wave][lane] = a2;
    __syncthreads();

    if (lane < E_) {
        float a3 = gb3[lane];
        for (int i = 0; i < GH; i++) a3 = fmaf(h[wave][i], gw3[i * E_ + lane], a3);
        lg[wave][lane] = a3;
    }
    __syncthreads();
    if (lane < E_) {
        float mx = lg[wave][0];
        for (int i = 1; i < E_; i++) mx = fmaxf(mx, lg[wave][i]);
        float s = 0.f;
        for (int i = 0; i < E_; i++) s += expf(lg[wave][i] - mx);
        coeff[(size_t)row * E_ + lane] = expf(lg[wave][lane] - mx) / s;
    }
}

// ---------------------------------------------------------------------------
// bf16 GEMM: Y[M, 4096] f32 = A[M,K] * Bt[4096,K]^T
// 64x128 block tile, BK=32, 4 waves x (32x64), mfma_f32_16x16x32_bf16.
// grid (4096/128=32, M/64=16) = 512 blocks -> 2 blocks/CU (vs 1 at 128x128).
// ---------------------------------------------------------------------------
__global__ __launch_bounds__(256) void gemm_bt(
    const __hip_bfloat16* __restrict__ A,
    const __hip_bfloat16* __restrict__ Bt,
    float* __restrict__ Y,
    int K)
{
    __shared__ __hip_bfloat16 As[64 * 32];    // 4 KiB
    __shared__ __hip_bfloat16 Bs[128 * 32];   // 8 KiB
    const int t = threadIdx.x;
    const int lane = t & 63, wave = t >> 6;
    const int n0 = blockIdx.x * 128;
    const int m0 = blockIdx.y * 64;
    const int mw = (wave >> 1) * 32, nw = (wave & 1) * 64;   // wave: 32 rows x 64 cols
    const int q = lane >> 4, r = lane & 15;
    const int rowc = lane >> 2, c16 = lane & 3;              // staging lane map

    f32x4 acc[2][4];
#pragma unroll
    for (int i = 0; i < 2; i++)
#pragma unroll
        for (int j = 0; j < 4; j++) acc[i][j] = (f32x4){0.f, 0.f, 0.f, 0.f};

    for (int k0 = 0; k0 < K; k0 += 32) {
        __syncthreads();
        // 12 chunks of (16 rows x 32 cols): 0..3 -> As, 4..11 -> Bs; 3 per wave
#pragma unroll
        for (int i = 0; i < 3; i++) {
            const int ch = wave + 4 * i;
            if (ch < 4) {
                const __hip_bfloat16* ga =
                    A + (size_t)(m0 + ch * 16 + rowc) * K + (k0 + c16 * 8);
                __builtin_amdgcn_global_load_lds(
                    (const __attribute__((address_space(1))) void*)ga,
                    (__attribute__((address_space(3))) void*)(As + ch * 512), 16, 0, 0);
            } else {
                const int cb = ch - 4;
                const __hip_bfloat16* gb =
                    Bt + (size_t)(n0 + cb * 16 + rowc) * K + (k0 + c16 * 8);
                __builtin_amdgcn_global_load_lds(
                    (const __attribute__((address_space(1))) void*)gb,
                    (__attribute__((address_space(3))) void*)(Bs + cb * 512), 16, 0, 0);
            }
        }
        __syncthreads();   // drains vmcnt(0): staged data visible to all waves

        bf16x8 af[2], bf[4];
#pragma unroll
        for (int im = 0; im < 2; im++)
            af[im] = *(const bf16x8*)(As + (mw + im * 16 + r) * 32 + q * 8);
#pragma unroll
        for (int in = 0; in < 4; in++)
            bf[in] = *(const bf16x8*)(Bs + (nw + in * 16 + r) * 32 + q * 8);
#pragma unroll
        for (int im = 0; im < 2; im++)
#pragma unroll
            for (int in = 0; in < 4; in++)
                acc[im][in] = __builtin_amdgcn_mfma_f32_16x16x32_bf16(
                    af[im], bf[in], acc[im][in], 0, 0, 0);
    }

    // Epilogue: D layout col=lane&15, row=(lane>>4)*4+reg  [m89-verified]
#pragma unroll
    for (int im = 0; im < 2; im++)
#pragma unroll
        for (int in = 0; in < 4; in++) {
            const int n = n0 + nw + in * 16 + r;
#pragma unroll
            for (int v = 0; v < 4; v++) {
                const int m = m0 + mw + im * 16 + q * 4 + v;
                Y[(size_t)m * NTOT + n] = acc[im][in][v];
            }
        }
}

// ---------------------------------------------------------------------------
// Expert reduce: out[b,o] = act( sum_e coeff[b,e] * (Y[b,e*512+o] + bias[e,o]) )
// Writes bf16 into xnext[:, 64:576] (layers 0,1) or f32 into fout (layer 2).
// grid 512, block 256; each thread does 4 columns (float4).
// ---------------------------------------------------------------------------
__global__ __launch_bounds__(256) void reduce_kernel(
    const float* __restrict__ Y, const float* __restrict__ coeff,
    const float* __restrict__ bias,
    __hip_bfloat16* __restrict__ xnext, float* __restrict__ fout,
    int applyElu)
{
    const int idx = blockIdx.x * 256 + threadIdx.x;   // B_*128 exactly
    const int b = idx >> 7;
    const int o = (idx & 127) * 4;
    const float* cb = coeff + (size_t)b * E_;
    f32x4 s = (f32x4){0.f, 0.f, 0.f, 0.f};
#pragma unroll
    for (int e = 0; e < E_; e++) {
        const float ce = cb[e];
        const f32x4 y  = *(const f32x4*)(Y + (size_t)b * NTOT + e * 512 + o);
        const f32x4 bs = *(const f32x4*)(bias + (size_t)e * 512 + o);
#pragma unroll
        for (int v = 0; v < 4; v++) s[v] += ce * (y[v] + bs[v]);
    }
    if (applyElu) {
#pragma unroll
        for (int v = 0; v < 4; v++) s[v] = elu_f(s[v]);
    }
    if (xnext) {
#pragma unroll
        for (int v = 0; v < 4; v++)
            xnext[(size_t)b * INTER + LAT + o + v] = __float2bfloat16(s[v]);
    } else {
#pragma unroll
        for (int v = 0; v < 4; v++) fout[(size_t)b * OUT_SZ + o + v] = s[v];
    }
}

// ---------------------------------------------------------------------------
static inline size_t align256(size_t x) { return (x + 255) & ~(size_t)255; }

extern "C" void kernel_launch(void* const* d_in, const int* in_sizes, int n_in,
                              void* d_out, int out_size, void* d_ws, size_t ws_size,
                              hipStream_t stream)
{
    const float* z   = (const float*)d_in[0];
    const float* c   = (const float*)d_in[1];
    const float* w0  = (const float*)d_in[2];
    const float* b0  = (const float*)d_in[3];
    const float* w1  = (const float*)d_in[4];
    const float* b1  = (const float*)d_in[5];
    const float* w2  = (const float*)d_in[6];
    const float* b2  = (const float*)d_in[7];
    const float* gw1 = (const float*)d_in[8];
    const float* gb1 = (const float*)d_in[9];
    const float* gw2 = (const float*)d_in[10];
    const float* gb2 = (const float*)d_in[11];
    const float* gw3 = (const float*)d_in[12];
    const float* gb3 = (const float*)d_in[13];
    float* out = (float*)d_out;

    uint8_t* p = (uint8_t*)d_ws;
    __hip_bfloat16* wT0 = (__hip_bfloat16*)p; p += align256((size_t)NTOT * IN_SZ * 2);
    __hip_bfloat16* wT1 = (__hip_bfloat16*)p; p += align256((size_t)NTOT * INTER * 2);
    __hip_bfloat16* wT2 = (__hip_bfloat16*)p; p += align256((size_t)NTOT * INTER * 2);
    __hip_bfloat16* x0  = (__hip_bfloat16*)p; p += align256((size_t)B_ * IN_SZ * 2);
    __hip_bfloat16* x1  = (__hip_bfloat16*)p; p += align256((size_t)B_ * INTER * 2);
    __hip_bfloat16* x2  = (__hip_bfloat16*)p; p += align256((size_t)B_ * INTER * 2);
    float* coeff        = (float*)p;          p += align256((size_t)B_ * E_ * 4);
    float* Y            = (float*)p;          p += align256((size_t)B_ * NTOT * 4);

    // 1) activations -> bf16
    xconv_kernel<<<(B_ * IN_SZ) / 256, 256, 0, stream>>>(z, c, x0, x1, x2);
    // 2) weights -> bf16 transposed [4096, K]
    wconv_kernel<<<dim3(16, IN_SZ / 32, E_), dim3(32, 8), 0, stream>>>(w0, wT0, IN_SZ);
    wconv_kernel<<<dim3(16, INTER / 32, E_), dim3(32, 8), 0, stream>>>(w1, wT1, INTER);
    wconv_kernel<<<dim3(16, INTER / 32, E_), dim3(32, 8), 0, stream>>>(w2, wT2, INTER);
    // 3) gating coefficients (f32 exact)
    gate_kernel<<<B_ / 4, 256, 0, stream>>>(z, c, gw1, gb1, gw2, gb2, gw3, gb3, coeff);

    // 4) layer 0: Y = x0 @ W0cat ; out0 = elu(reduce) -> x1[:,64:]
    gemm_bt<<<dim3(NTOT / 128, B_ / 64), 256, 0, stream>>>(x0, wT0, Y, IN_SZ);
    reduce_kernel<<<(B_ * 128) / 256, 256, 0, stream>>>(Y, coeff, b0, x1, nullptr, 1);
    // 5) layer 1
    gemm_bt<<<dim3(NTOT / 128, B_ / 64), 256, 0, stream>>>(x1, wT1, Y, INTER);
    reduce_kernel<<<(B_ * 128) / 256, 256, 0, stream>>>(Y, coeff, b1, x2, nullptr, 1);
    // 6) layer 2 -> d_out (f32, no act)
    gemm_bt<<<dim3(NTOT / 128, B_ / 64), 256, 0, stream>>>(x2, wT2, Y, INTER);
    reduce_kernel<<<(B_ * 128) / 256, 256, 0, stream>>>(Y, coeff, b2, nullptr, out, 0);
}

// Round 3
// 167.221 us; speedup vs baseline: 1.1050x; 1.0275x over previous
//
#include <hip/hip_runtime.h>
#include <hip/hip_bf16.h>
#include <stdint.h>
#include <math.h>

// Problem dims
#define B_    1024
#define LAT   64
#define FCON  256
#define IN_SZ 320          // LAT + FCON
#define HID   512
#define E_    8
#define GH    64
#define INTER 576          // LAT + HID
#define OUT_SZ 512
#define NTOT  4096         // E_ * 512
#define KI0   10           // IN_SZ/32
#define KI12  18           // INTER/32

typedef __attribute__((ext_vector_type(8))) __bf16 bf16x8;
typedef __attribute__((ext_vector_type(4))) __bf16 bf16x4;
typedef __attribute__((ext_vector_type(4))) float  f32x4;

__device__ __forceinline__ float elu_f(float x) { return x > 0.f ? x : expf(x) - 1.f; }
__device__ __forceinline__ __bf16 to_bf16(float f) {
    __hip_bfloat16 h = __float2bfloat16(f);
    return *reinterpret_cast<__bf16*>(&h);
}

// ---------------------------------------------------------------------------
// Fragment layout (matches mfma_f32_16x16x32_bf16 A/B operand, m89-verified):
//   frag(t0,k0)[lane][j] = X[t0 + (lane&15)][k0 + (lane>>4)*8 + j],  j=0..7
// Packed storage: buf[(tile_idx*KI + ki)*64 + lane] : bf16x8 (16 B/lane).
// ---------------------------------------------------------------------------

// Pack z,c into A-fragments. z-frags (ki 0,1) go to Ap0, Ap1, Ap2.
// c-frags (ki 2..9) go to Ap0 only. One wave per fragment; 640 waves.
__global__ __launch_bounds__(256) void zcpack_kernel(
    const float* __restrict__ z, const float* __restrict__ c,
    bf16x8* __restrict__ Ap0, bf16x8* __restrict__ Ap1, bf16x8* __restrict__ Ap2)
{
    const int wid  = blockIdx.x * 4 + (threadIdx.x >> 6);
    const int lane = threadIdx.x & 63, q = lane >> 4, r = lane & 15;
    bf16x8 v;
    if (wid < 128) {                       // z fragment: mi in [0,64), ki in {0,1}
        const int mi = wid >> 1, ki = wid & 1;
        const float* src = z + (size_t)(mi * 16 + r) * LAT + ki * 32 + q * 8;
        const f32x4 lo = *(const f32x4*)src, hi = *(const f32x4*)(src + 4);
#pragma unroll
        for (int j = 0; j < 4; j++) { v[j] = to_bf16(lo[j]); v[j + 4] = to_bf16(hi[j]); }
        Ap0[((size_t)mi * KI0  + ki) * 64 + lane] = v;
        Ap1[((size_t)mi * KI12 + ki) * 64 + lane] = v;
        Ap2[((size_t)mi * KI12 + ki) * 64 + lane] = v;
    } else {                               // c fragment: ki in [2,10)
        const int cid = wid - 128;
        const int mi = cid >> 3, ki = 2 + (cid & 7);
        const float* src = c + (size_t)(mi * 16 + r) * FCON + (ki - 2) * 32 + q * 8;
        const f32x4 lo = *(const f32x4*)src, hi = *(const f32x4*)(src + 4);
#pragma unroll
        for (int j = 0; j < 4; j++) { v[j] = to_bf16(lo[j]); v[j + 4] = to_bf16(hi[j]); }
        Ap0[((size_t)mi * KI0 + ki) * 64 + lane] = v;
    }
}

// Pack weights w [E, K, 512] f32 into B-fragments over n = e*512+o.
// grid (KI, 64), block 256 (4 waves); one wave per fragment (ni, ki).
__global__ __launch_bounds__(256) void wpack_kernel(
    const float* __restrict__ w, bf16x8* __restrict__ Wp, int K, int KI)
{
    const int ki = blockIdx.x;
    const int ni = blockIdx.y * 4 + (threadIdx.x >> 6);
    const int lane = threadIdx.x & 63, q = lane >> 4, r = lane & 15;
    const int n = ni * 16 + r, e = n >> 9, o = n & 511;
    const float* src = w + (size_t)e * K * 512 + (size_t)(ki * 32 + q * 8) * 512 + o;
    bf16x8 v;
#pragma unroll
    for (int j = 0; j < 8; j++) v[j] = to_bf16(src[(size_t)j * 512]);
    Wp[((size_t)ni * KI + ki) * 64 + lane] = v;
}

// ---------------------------------------------------------------------------
// Gating network (f32 exact): coeff = softmax(elu(elu(x@gw1+gb1)@gw2+gb2)@gw3+gb3)
// ---------------------------------------------------------------------------
__global__ __launch_bounds__(256) void gate_kernel(
    const float* __restrict__ z, const float* __restrict__ c,
    const float* __restrict__ gw1, const float* __restrict__ gb1,
    const float* __restrict__ gw2, const float* __restrict__ gb2,
    const float* __restrict__ gw3, const float* __restrict__ gb3,
    float* __restrict__ coeff)
{
    __shared__ float h[4][GH];
    __shared__ float lg[4][E_];
    const int lane = threadIdx.x & 63, wave = threadIdx.x >> 6;
    const int row = blockIdx.x * 4 + wave;
    const float* zr = z + (size_t)row * LAT;
    const float* cr = c + (size_t)row * FCON;

    float a1 = gb1[lane];
    for (int i = 0; i < LAT; i++)  a1 = fmaf(zr[i], gw1[i * GH + lane], a1);
    for (int i = 0; i < FCON; i++) a1 = fmaf(cr[i], gw1[(LAT + i) * GH + lane], a1);
    h[wave][lane] = elu_f(a1);
    __syncthreads();

    float a2 = gb2[lane];
    for (int i = 0; i < GH; i++) a2 = fmaf(h[wave][i], gw2[i * GH + lane], a2);
    a2 = elu_f(a2);
    __syncthreads();
    h[wave][lane] = a2;
    __syncthreads();

    if (lane < E_) {
        float a3 = gb3[lane];
        for (int i = 0; i < GH; i++) a3 = fmaf(h[wave][i], gw3[i * E_ + lane], a3);
        lg[wave][lane] = a3;
    }
    __syncthreads();
    if (lane < E_) {
        float mx = lg[wave][0];
        for (int i = 1; i < E_; i++) mx = fmaxf(mx, lg[wave][i]);
        float s = 0.f;
        for (int i = 0; i < E_; i++) s += expf(lg[wave][i] - mx);
        coeff[(size_t)row * E_ + lane] = expf(lg[wave][lane] - mx) / s;
    }
}

// ---------------------------------------------------------------------------
// Barrier-free fragment-direct GEMM: Y[1024, 4096] f32 = A * W^T from packed
// fragments. No LDS, no __syncthreads — compiler software-pipelines the
// global->VGPR fragment loads with fine-grained vmcnt (AITER-style).
// Block tile 64m x 128n, wave tile 32m x 64n. grid (32 n-tiles, 16 m-tiles)
// = 512 blocks -> 2 blocks/CU. XCD affinity: n-tile == blockIdx.x % 8.
// ---------------------------------------------------------------------------
template<int KI>
__global__ __launch_bounds__(256, 2) void gemm_frag(
    const bf16x8* __restrict__ Ap, const bf16x8* __restrict__ Wp,
    float* __restrict__ Y)
{
    const int t = threadIdx.x;
    const int lane = t & 63, wave = t >> 6;
    const int n0 = blockIdx.x * 128;
    const int m0 = blockIdx.y * 64;
    const int mw = (wave >> 1) * 32, nw = (wave & 1) * 64;
    const int q = lane >> 4, r = lane & 15;
    const int miB = (m0 + mw) >> 4;     // first a-frag tile index (2 per wave)
    const int niB = (n0 + nw) >> 4;     // first b-frag tile index (4 per wave)

    const bf16x8* aBase = Ap + (size_t)miB * KI * 64 + lane;
    const bf16x8* bBase = Wp + (size_t)niB * KI * 64 + lane;

    f32x4 acc[2][4];
#pragma unroll
    for (int i = 0; i < 2; i++)
#pragma unroll
        for (int j = 0; j < 4; j++) acc[i][j] = (f32x4){0.f, 0.f, 0.f, 0.f};

#pragma unroll
    for (int ki = 0; ki < KI; ++ki) {
        bf16x8 af[2], bf[4];
#pragma unroll
        for (int im = 0; im < 2; im++) af[im] = aBase[((size_t)im * KI + ki) * 64];
#pragma unroll
        for (int in = 0; in < 4; in++) bf[in] = bBase[((size_t)in * KI + ki) * 64];
#pragma unroll
        for (int im = 0; im < 2; im++)
#pragma unroll
            for (int in = 0; in < 4; in++)
                acc[im][in] = __builtin_amdgcn_mfma_f32_16x16x32_bf16(
                    af[im], bf[in], acc[im][in], 0, 0, 0);
    }

    // D layout: col = lane&15, row = (lane>>4)*4 + reg  [m89-verified]
#pragma unroll
    for (int im = 0; im < 2; im++)
#pragma unroll
        for (int in = 0; in < 4; in++) {
            const int n = n0 + nw + in * 16 + r;
#pragma unroll
            for (int v = 0; v < 4; v++) {
                const int m = m0 + mw + im * 16 + q * 4 + v;
                Y[(size_t)m * NTOT + n] = acc[im][in][v];
            }
        }
}

// ---------------------------------------------------------------------------
// Expert reduce: s[b,o] = sum_e coeff[b,e] * (Y[b,e*512+o] + bias[e,o]).
// FINAL=0: elu(s) -> packed A-fragments of the next layer (k = 64+o, KI12).
// FINAL=1: s -> f32 d_out.
// grid 512, block 256; thread handles 4 consecutive o.
// ---------------------------------------------------------------------------
template<int FINAL>
__global__ __launch_bounds__(256) void reduce_kernel(
    const float* __restrict__ Y, const float* __restrict__ coeff,
    const float* __restrict__ bias,
    bf16x4* __restrict__ ApN, float* __restrict__ fout)
{
    const int idx = blockIdx.x * 256 + threadIdx.x;   // B_*128 exactly
    const int b = idx >> 7;
    const int o = (idx & 127) * 4;
    const float* cb = coeff + (size_t)b * E_;
    f32x4 s = (f32x4){0.f, 0.f, 0.f, 0.f};
#pragma unroll
    for (int e = 0; e < E_; e++) {
        const float ce = cb[e];
        const f32x4 y  = *(const f32x4*)(Y + (size_t)b * NTOT + e * 512 + o);
        const f32x4 bs = *(const f32x4*)(bias + (size_t)e * 512 + o);
#pragma unroll
        for (int v = 0; v < 4; v++) s[v] += ce * (y[v] + bs[v]);
    }
    if (FINAL) {
        *(f32x4*)(fout + (size_t)b * OUT_SZ + o) = s;
    } else {
#pragma unroll
        for (int v = 0; v < 4; v++) s[v] = elu_f(s[v]);
        bf16x4 vq;
#pragma unroll
        for (int v = 0; v < 4; v++) vq[v] = to_bf16(s[v]);
        const int k  = LAT + o;
        const int mi = b >> 4, r = b & 15;
        const int ki = k >> 5, kq = (k & 31) >> 3, jb = k & 7;   // jb in {0,4}
        // bf16 element offset = (((mi*KI12+ki)*64 + kq*16 + r)*8 + jb); /4 -> bf16x4 idx
        ApN[(((size_t)mi * KI12 + ki) * 64 + kq * 16 + r) * 2 + (jb >> 2)] = vq;
    }
}

// ---------------------------------------------------------------------------
static inline size_t align256(size_t x) { return (x + 255) & ~(size_t)255; }

extern "C" void kernel_launch(void* const* d_in, const int* in_sizes, int n_in,
                              void* d_out, int out_size, void* d_ws, size_t ws_size,
                              hipStream_t stream)
{
    const float* z   = (const float*)d_in[0];
    const float* c   = (const float*)d_in[1];
    const float* w0  = (const float*)d_in[2];
    const float* b0  = (const float*)d_in[3];
    const float* w1  = (const float*)d_in[4];
    const float* b1  = (const float*)d_in[5];
    const float* w2  = (const float*)d_in[6];
    const float* b2  = (const float*)d_in[7];
    const float* gw1 = (const float*)d_in[8];
    const float* gb1 = (const float*)d_in[9];
    const float* gw2 = (const float*)d_in[10];
    const float* gb2 = (const float*)d_in[11];
    const float* gw3 = (const float*)d_in[12];
    const float* gb3 = (const float*)d_in[13];
    float* out = (float*)d_out;

    uint8_t* p = (uint8_t*)d_ws;
    bf16x8* Wp0 = (bf16x8*)p; p += align256((size_t)NTOT * IN_SZ * 2);
    bf16x8* Wp1 = (bf16x8*)p; p += align256((size_t)NTOT * INTER * 2);
    bf16x8* Wp2 = (bf16x8*)p; p += align256((size_t)NTOT * INTER * 2);
    bf16x8* Ap0 = (bf16x8*)p; p += align256((size_t)B_ * IN_SZ * 2);
    bf16x8* Ap1 = (bf16x8*)p; p += align256((size_t)B_ * INTER * 2);
    bf16x8* Ap2 = (bf16x8*)p; p += align256((size_t)B_ * INTER * 2);
    float* coeff = (float*)p; p += align256((size_t)B_ * E_ * 4);
    float* Y     = (float*)p; p += align256((size_t)B_ * NTOT * 4);

    // 1) pack activations (z,c) into A-fragments for all three layers
    zcpack_kernel<<<160, 256, 0, stream>>>(z, c, Ap0, Ap1, Ap2);
    // 2) pack weights into B-fragments
    wpack_kernel<<<dim3(KI0,  64), 256, 0, stream>>>(w0, Wp0, IN_SZ, KI0);
    wpack_kernel<<<dim3(KI12, 64), 256, 0, stream>>>(w1, Wp1, INTER, KI12);
    wpack_kernel<<<dim3(KI12, 64), 256, 0, stream>>>(w2, Wp2, INTER, KI12);
    // 3) gating coefficients (f32 exact)
    gate_kernel<<<B_ / 4, 256, 0, stream>>>(z, c, gw1, gb1, gw2, gb2, gw3, gb3, coeff);

    // 4) layer 0
    gemm_frag<KI0><<<dim3(32, 16), 256, 0, stream>>>(Ap0, Wp0, Y);
    reduce_kernel<0><<<512, 256, 0, stream>>>(Y, coeff, b0, (bf16x4*)Ap1, nullptr);
    // 5) layer 1
    gemm_frag<KI12><<<dim3(32, 16), 256, 0, stream>>>(Ap1, Wp1, Y);
    reduce_kernel<0><<<512, 256, 0, stream>>>(Y, coeff, b1, (bf16x4*)Ap2, nullptr);
    // 6) layer 2 -> d_out (f32, no act)
    gemm_frag<KI12><<<dim3(32, 16), 256, 0, stream>>>(Ap2, Wp2, Y);
    reduce_kernel<1><<<512, 256, 0, stream>>>(Y, coeff, b2, nullptr, out);
}